// Round 10
// baseline (460.073 us; speedup 1.0000x reference)
//
#include <hip/hip_runtime.h>

// y[n] = beta0 + sum_c X[n,c]*(beta[c] + Z[n,c]),  Z = X @ triu(Theta,1)
// R10 = R9 + occupancy & locality: 512 threads (8 waves x 64 rows),
// ROWS_PER_BLK=512 -> 16 waves/CU (4/SIMD, was 2); XCD-grouped scheduling
// (all 20 panels of an m-chunk consecutive on one XCD -> X served from L2,
// not HBM). Design unchanged otherwise: B-stationary panel (64 KB LDS,
// staged once, single barrier), barrier-free M-stream of {2 A-loads,
// 8 ds_read_b128, 16 MFMA} per kk, transposed MFMA D[c,n], fused
// contraction reads X row-contiguously, y via atomicAdd.

typedef __bf16 bf16_t;
typedef bf16_t bf16x8 __attribute__((ext_vector_type(8)));
typedef float f32x4 __attribute__((ext_vector_type(4)));
typedef unsigned short u16;
typedef u16 u16x4 __attribute__((ext_vector_type(4)));
typedef u16 u16x8 __attribute__((ext_vector_type(8)));

#define N_ROWS 65536
#define P_DIM  1024
#define ROWS_PER_BLK 512
#define NPANEL 20

static __device__ __forceinline__ u16 f2bf(float f) {
  unsigned u = __builtin_bit_cast(unsigned, f);
  u += 0x7FFFu + ((u >> 16) & 1u);   // round-to-nearest-even
  return (u16)(u >> 16);
}
static __device__ __forceinline__ float bf2f(u16 v) {
  return __builtin_bit_cast(float, ((unsigned)v) << 16);
}

// global(16B/lane, per-lane src) -> LDS direct (wave-uniform dest + lane*16).
static __device__ __forceinline__ void gload16(const void* g, void* lds_base) {
  __builtin_amdgcn_global_load_lds(
      (const __attribute__((address_space(1))) unsigned char*)g,
      (__attribute__((address_space(3))) unsigned char*)lds_base, 16, 0, 0);
}

__global__ void __launch_bounds__(256)
zero_y(float* __restrict__ y) {
  int i = blockIdx.x * blockDim.x + threadIdx.x;
  if (i < N_ROWS) y[i] = 0.0f;
}

__global__ void __launch_bounds__(256)
init_y(float* __restrict__ y, const float* __restrict__ beta0) {
  int i = blockIdx.x * blockDim.x + threadIdx.x;
  if (i < N_ROWS) y[i] = beta0[0];
}

// ---- conv 1: X f32 -> bf16, LINEAR layout ----
__global__ void __launch_bounds__(256)
conv_x(const float* __restrict__ X, u16* __restrict__ Xb) {
  const size_t total8 = (size_t)N_ROWS * P_DIM / 8;
  const size_t stride = (size_t)gridDim.x * 256;
  for (size_t i = (size_t)blockIdx.x * 256 + threadIdx.x; i < total8; i += stride) {
    f32x4 a = *(const f32x4*)(X + i * 8);
    f32x4 b = *(const f32x4*)(X + i * 8 + 4);
    u16x8 w;
    #pragma unroll
    for (int j = 0; j < 4; ++j) { w[j] = f2bf(a[j]); w[j + 4] = f2bf(b[j]); }
    *(u16x8*)(Xb + i * 8) = w;
  }
}

// ---- conv 2: Tt[c][Q'] = quad Q = Q'^(c&7) of column c, triu-masked:
// elems k=8Q..8Q+7, value = (k<c) ? bf16(Theta[k][c]) : 0. Quad-XOR baked in
// so the GEMM stages linearly (gload16) and reads conflict-free (rule 21).
__global__ void __launch_bounds__(128)
conv_theta(const float* __restrict__ Theta, u16* __restrict__ Tt) {
  __shared__ float tile[32][33];
  const int tid = threadIdx.x;         // 0..127
  const int k0  = blockIdx.x * 32;
  const int c0  = blockIdx.y * 32;
  {
    const int tx = tid & 31;           // c within tile
    const int rb = tid >> 5;           // 0..3
    #pragma unroll
    for (int i = 0; i < 8; ++i) {
      int kl = rb * 8 + i;
      tile[kl][tx] = Theta[(size_t)(k0 + kl) * P_DIM + c0 + tx];
    }
  }
  __syncthreads();
  {
    const int cl = tid >> 2;           // 0..31
    const int qt = tid & 3;            // quad within this 32-k tile
    const int c  = c0 + cl;
    const int Q  = blockIdx.x * 4 + qt;  // global quad 0..127
    u16x8 w;
    #pragma unroll
    for (int e = 0; e < 8; ++e) {
      int k = Q * 8 + e;
      float v = tile[qt * 8 + e][cl];
      w[e] = (k < c) ? f2bf(v) : (u16)0;
    }
    *(u16x8*)(Tt + (size_t)c * P_DIM + (size_t)((Q ^ (c & 7)) * 8)) = w;
  }
}

// ---- main kernel: B-stationary panel GEMM + fused contraction ----
__global__ void __launch_bounds__(512, 4)
gemm_bstat(const u16* __restrict__ Xb, const u16* __restrict__ Tt,
           const float* __restrict__ beta, const float* __restrict__ beta0,
           float* __restrict__ y)
{
  __shared__ __align__(16) u16 B[128 * 256];   // 64 KB: [c 128][k 256], rows 512B

  // XCD-grouped mapping: blocks on XCD x (bid&7==x, assuming round-robin
  // bid->XCD) iterate the 20 panels of ONE m-chunk consecutively -> the
  // 1 MB X chunk is re-used ~4.6x from that XCD's L2 instead of HBM.
  const int bid  = blockIdx.x;         // 0..2559
  const int xcd  = bid & 7;
  const int loc  = bid >> 3;           // 0..319
  const int mcl  = loc / NPANEL;       // 0..15
  const int pid  = loc % NPANEL;
  const int m0   = (mcl * 8 + xcd) * ROWS_PER_BLK;

  // pid -> (cc, kc): kc-chunks per cc = (cc+2)>>1, cum = 1,2,4,6,9,12,16,20
  int cc = 0, base = 0;
  #pragma unroll
  for (int j = 0; j < 8; ++j) {
    int kcj = (j + 2) >> 1;
    if (pid >= base + kcj) { base += kcj; cc = j + 1; }
  }
  const int kc    = pid - base;
  const int kbeg  = kc * 256;
  const int krem  = 128 * (cc + 1) - kbeg;
  const int kkcnt = krem >= 256 ? 8 : 4;       // 8 or 4 (krem is 128 or >=256)
  const int c0    = cc * 128;
  const bool add_beta = (kc == 0);
  const bool add_b0   = (cc == 0 && kc == 0);
  const float b0 = beta0[0];

  const int tid  = threadIdx.x;
  const int lane = tid & 63;
  const int w    = tid >> 6;           // wave 0..7
  const int l15  = lane & 15;
  const int lg   = lane >> 4;

  // ---- stage B panel (once): wave w covers c-pairs [8w, 8w+8) ----
  // Instr i: 1 KB = 2 c-rows; lanes 0..31 -> local c=2pi (512B), 32..63 -> 2pi+1.
  // Source is PRE-SWIZZLED Tt at GLOBAL column c0+c.
  #pragma unroll
  for (int i = 0; i < 8; ++i) {
    const int pi = w * 8 + i;
    const int c  = 2 * pi + (lane >> 5);
    gload16(Tt + (size_t)(c0 + c) * P_DIM + kbeg + (lane & 31) * 8, &B[pi * 512]);
  }
  asm volatile("s_waitcnt vmcnt(0)" ::: "memory");
  __builtin_amdgcn_sched_barrier(0);
  __builtin_amdgcn_s_barrier();
  __builtin_amdgcn_sched_barrier(0);

  // ---- barrier-free M-stream: wave w owns rows [m0+64w, m0+64w+64) ----
  const int rbase = m0 + w * 64;

  #define KKBODY(KK)                                                            \
    _Pragma("unroll")                                                           \
    for (int kk = 0; kk < (KK); ++kk) {                                         \
      bf16x8 a0, a1, bfr[8];                                                    \
      {                                                                         \
        u16x8 v = *(const u16x8*)(Xb + (size_t)(rowA + l15) * P_DIM + kbeg + kk * 32 + lg * 8); \
        a0 = __builtin_bit_cast(bf16x8, v);                                     \
      }                                                                         \
      {                                                                         \
        u16x8 v = *(const u16x8*)(Xb + (size_t)(rowB + l15) * P_DIM + kbeg + kk * 32 + lg * 8); \
        a1 = __builtin_bit_cast(bf16x8, v);                                     \
      }                                                                         \
      _Pragma("unroll")                                                         \
      for (int ni = 0; ni < 8; ++ni) {                                          \
        const int c_ = ni * 16 + l15;                                           \
        const int qp = (kk * 4 + lg) ^ (c_ & 7);                                \
        u16x8 v = *(const u16x8*)&B[c_ * 256 + qp * 8];                         \
        bfr[ni] = __builtin_bit_cast(bf16x8, v);                                \
      }                                                                         \
      _Pragma("unroll")                                                         \
      for (int ni = 0; ni < 8; ++ni) {                                          \
        acc0[ni] = __builtin_amdgcn_mfma_f32_16x16x32_bf16(bfr[ni], a0, acc0[ni], 0, 0, 0); \
        acc1[ni] = __builtin_amdgcn_mfma_f32_16x16x32_bf16(bfr[ni], a1, acc1[ni], 0, 0, 0); \
      }                                                                         \
    }

  // Contraction: lane holds D[c,n] with n = ROW+l15, c = c0 + ni*16 + lg*4 + r.
  #define CONTRACT(ACC, ROW)                                                    \
    {                                                                           \
      float ys = 0.0f;                                                          \
      _Pragma("unroll")                                                         \
      for (int ni = 0; ni < 8; ++ni) {                                          \
        u16x4 xw = *(const u16x4*)(Xb + (size_t)((ROW) + l15) * P_DIM + c0 + ni * 16 + lg * 4); \
        f32x4 bv = add_beta ? *(const f32x4*)(beta + c0 + ni * 16 + lg * 4) : (f32x4)0.0f; \
        _Pragma("unroll")                                                       \
        for (int r = 0; r < 4; ++r)                                             \
          ys += (ACC[ni][r] + bv[r]) * bf2f(xw[r]);                             \
      }                                                                         \
      ys += __shfl_xor(ys, 16);                                                 \
      ys += __shfl_xor(ys, 32);                                                 \
      if (lane < 16) {                                                          \
        if (add_b0) ys += b0;                                                   \
        atomicAdd(&y[(ROW) + l15], ys);                                        \
      }                                                                         \
    }

  #pragma unroll
  for (int p = 0; p < 2; ++p) {
    const int rowA = rbase + p * 32;
    const int rowB = rowA + 16;
    f32x4 acc0[8], acc1[8];
    #pragma unroll
    for (int ni = 0; ni < 8; ++ni) { acc0[ni] = (f32x4)0.0f; acc1[ni] = (f32x4)0.0f; }

    if (kkcnt == 8) { KKBODY(8) } else { KKBODY(4) }

    CONTRACT(acc0, rowA)
    CONTRACT(acc1, rowB)
  }
  #undef KKBODY
  #undef CONTRACT
}

// ================= fallback (R1 kernel, 128x128) if ws too small =================
#define LDT 40
__global__ void __launch_bounds__(256)
fused_quad_fallback(const float* __restrict__ X, const float* __restrict__ beta,
                    const float* __restrict__ Theta, float* __restrict__ y)
{
  __shared__ __align__(16) u16 Alds[128 * LDT];
  __shared__ __align__(16) u16 Blds[128 * LDT];

  const int bid = blockIdx.x;
  const int bn  = bid & 7;
  const int bm  = bid >> 3;
  const int c0  = bn * 128;
  const int m0  = bm * 128;
  const int nkt = (bn + 1) * 4;

  const int tid  = threadIdx.x;
  const int lane = tid & 63;
  const int wid  = tid >> 6;
  const int wm   = wid >> 1;
  const int wn   = wid & 1;
  const int l15  = lane & 15;
  const int lg   = lane >> 4;

  f32x4 acc[4][4];
  #pragma unroll
  for (int i = 0; i < 4; ++i)
    #pragma unroll
    for (int j = 0; j < 4; ++j)
      acc[i][j] = (f32x4)0.0f;

  const int arow  = tid >> 1;
  const int ahalf = (tid & 1) * 16;
  const int kb4 = (tid >> 5) * 4;
  const int cb4 = (tid & 31) * 4;

  for (int kt = 0; kt < nkt; ++kt) {
    const int k0 = kt * 32;
    __syncthreads();
    {
      const f32x4* p = (const f32x4*)(X + (size_t)(m0 + arow) * P_DIM + k0 + ahalf);
      f32x4 v0 = p[0], v1 = p[1], v2 = p[2], v3 = p[3];
      u16x8 w0, w1;
      #pragma unroll
      for (int i = 0; i < 4; ++i) {
        w0[i] = f2bf(v0[i]); w0[i + 4] = f2bf(v1[i]);
        w1[i] = f2bf(v2[i]); w1[i + 4] = f2bf(v3[i]);
      }
      *(u16x8*)&Alds[arow * LDT + ahalf]     = w0;
      *(u16x8*)&Alds[arow * LDT + ahalf + 8] = w1;
    }
    {
      float e[4][4];
      #pragma unroll
      for (int i = 0; i < 4; ++i) {
        f32x4 r = *(const f32x4*)(Theta + (size_t)(k0 + kb4 + i) * P_DIM + c0 + cb4);
        #pragma unroll
        for (int j = 0; j < 4; ++j)
          e[i][j] = ((k0 + kb4 + i) < (c0 + cb4 + j)) ? r[j] : 0.0f;
      }
      #pragma unroll
      for (int j = 0; j < 4; ++j) {
        u16x4 wv;
        #pragma unroll
        for (int i = 0; i < 4; ++i) wv[i] = f2bf(e[i][j]);
        *(u16x4*)&Blds[(cb4 + j) * LDT + kb4] = wv;
      }
    }
    __syncthreads();

    bf16x8 af[4], bfr[4];
    #pragma unroll
    for (int mi = 0; mi < 4; ++mi) {
      u16x8 t = *(const u16x8*)&Alds[(wm * 64 + mi * 16 + l15) * LDT + lg * 8];
      af[mi] = __builtin_bit_cast(bf16x8, t);
    }
    #pragma unroll
    for (int ni = 0; ni < 4; ++ni) {
      u16x8 t = *(const u16x8*)&Blds[(wn * 64 + ni * 16 + l15) * LDT + lg * 8];
      bfr[ni] = __builtin_bit_cast(bf16x8, t);
    }
    #pragma unroll
    for (int mi = 0; mi < 4; ++mi)
      #pragma unroll
      for (int ni = 0; ni < 4; ++ni)
        acc[mi][ni] = __builtin_amdgcn_mfma_f32_16x16x32_bf16(af[mi], bfr[ni], acc[mi][ni], 0, 0, 0);
  }

  float ysum[4][4];
  #pragma unroll
  for (int mi = 0; mi < 4; ++mi)
    #pragma unroll
    for (int r = 0; r < 4; ++r)
      ysum[mi][r] = 0.0f;

  #pragma unroll
  for (int ni = 0; ni < 4; ++ni) {
    const int col = c0 + wn * 64 + ni * 16 + l15;
    const float bta = beta[col];
    #pragma unroll
    for (int mi = 0; mi < 4; ++mi) {
      const int rowb = m0 + wm * 64 + mi * 16 + lg * 4;
      #pragma unroll
      for (int r = 0; r < 4; ++r) {
        float xv = X[(size_t)(rowb + r) * P_DIM + col];
        ysum[mi][r] += (acc[mi][ni][r] + bta) * xv;
      }
    }
  }

  #pragma unroll
  for (int m = 1; m < 16; m <<= 1)
    #pragma unroll
    for (int mi = 0; mi < 4; ++mi)
      #pragma unroll
      for (int r = 0; r < 4; ++r)
        ysum[mi][r] += __shfl_xor(ysum[mi][r], m);

  if (l15 == 0) {
    #pragma unroll
    for (int mi = 0; mi < 4; ++mi)
      #pragma unroll
      for (int r = 0; r < 4; ++r)
        atomicAdd(&y[m0 + wm * 64 + mi * 16 + lg * 4 + r], ysum[mi][r]);
  }
}

extern "C" void kernel_launch(void* const* d_in, const int* in_sizes, int n_in,
                              void* d_out, int out_size, void* d_ws, size_t ws_size,
                              hipStream_t stream) {
  const float* X     = (const float*)d_in[0];
  const float* beta0 = (const float*)d_in[1];
  const float* beta  = (const float*)d_in[2];
  const float* Theta = (const float*)d_in[3];
  float* y = (float*)d_out;

  const size_t need = (size_t)N_ROWS * P_DIM * 2 + (size_t)P_DIM * P_DIM * 2;
  if (ws_size >= need) {
    u16* Xb = (u16*)d_ws;
    u16* Tt = Xb + (size_t)N_ROWS * P_DIM;
    zero_y<<<N_ROWS / 256, 256, 0, stream>>>(y);
    conv_x<<<2048, 256, 0, stream>>>(X, Xb);
    conv_theta<<<dim3(32, 32), 128, 0, stream>>>(Theta, Tt);
    gemm_bstat<<<(N_ROWS / ROWS_PER_BLK) * NPANEL, 512, 0, stream>>>(Xb, Tt, beta, beta0, y);
  } else {
    init_y<<<N_ROWS / 256, 256, 0, stream>>>(y, beta0);
    fused_quad_fallback<<<(N_ROWS / 128) * (P_DIM / 128), 256, 0, stream>>>(X, beta, Theta, y);
  }
}

// Round 11
// 199.492 us; speedup vs baseline: 2.3062x; 2.3062x over previous
//
#include <hip/hip_runtime.h>

// y[n] = beta0 + sum_c X[n,c]*(beta[c] + Z[n,c]),  Z = X @ triu(Theta,1)
// R11 = R3 evolved: BK=64 (half the vmcnt(0) drains), 8 waves/512 thr
// (wave tile 32x64, low VGPR, 2 blocks/CU), and segment-local quad-XOR
// LDS swizzle baked into BOTH conv outputs (staging stays linear
// global_load_lds; frag reads XOR the quad index) -> bank-conflict-free
// ds_read_b128 (R3 had 8-way, 9.4M cycles). XCD swizzle + heavy-first LPT.

typedef __bf16 bf16_t;
typedef bf16_t bf16x8 __attribute__((ext_vector_type(8)));
typedef float f32x4 __attribute__((ext_vector_type(4)));
typedef unsigned short u16;
typedef u16 u16x4 __attribute__((ext_vector_type(4)));
typedef u16 u16x8 __attribute__((ext_vector_type(8)));

#define N_ROWS 65536
#define P_DIM  1024
#define BM 128
#define BN 128
#define BK 64

static __device__ __forceinline__ u16 f2bf(float f) {
  unsigned u = __builtin_bit_cast(unsigned, f);
  u += 0x7FFFu + ((u >> 16) & 1u);   // round-to-nearest-even
  return (u16)(u >> 16);
}
static __device__ __forceinline__ float bf2f(u16 v) {
  return __builtin_bit_cast(float, ((unsigned)v) << 16);
}

// global(16B/lane, per-lane src) -> LDS direct (wave-uniform dest + lane*16).
static __device__ __forceinline__ void gload16(const void* g, void* lds_base) {
  __builtin_amdgcn_global_load_lds(
      (const __attribute__((address_space(1))) unsigned char*)g,
      (__attribute__((address_space(3))) unsigned char*)lds_base, 16, 0, 0);
}

__global__ void __launch_bounds__(256)
init_y(float* __restrict__ y, const float* __restrict__ beta0) {
  int i = blockIdx.x * blockDim.x + threadIdx.x;
  if (i < N_ROWS) y[i] = beta0[0];
}

// ---- conv 1: X f32 -> bf16 with segment-local quad-XOR:
// quad q (8 elems) of row r stored at quad position q ^ (r&7) (flips only
// the low 3 bits -> stays inside its 8-quad / 64-elem K-segment).
__global__ void __launch_bounds__(256)
conv_x(const float* __restrict__ X, u16* __restrict__ Xb) {
  const size_t nq = (size_t)N_ROWS * P_DIM / 8;
  const size_t stride = (size_t)gridDim.x * 256;
  for (size_t i = (size_t)blockIdx.x * 256 + threadIdx.x; i < nq; i += stride) {
    const int row = (int)(i >> 7);
    const int q   = (int)(i & 127);
    f32x4 a = *(const f32x4*)(X + i * 8);
    f32x4 b = *(const f32x4*)(X + i * 8 + 4);
    u16x8 w;
    #pragma unroll
    for (int j = 0; j < 4; ++j) { w[j] = f2bf(a[j]); w[j + 4] = f2bf(b[j]); }
    *(u16x8*)(Xb + (size_t)row * P_DIM + (size_t)((q ^ (row & 7)) * 8)) = w;
  }
}

// ---- conv 2: Tt[c][q'] with q' = q ^ (c&7), quad q = triu-masked bf16 of
// Theta[8q..8q+8, c] (transposed). Same segment-local involution as conv_x.
__global__ void __launch_bounds__(128)
conv_theta(const float* __restrict__ Theta, u16* __restrict__ Tt) {
  __shared__ float tile[32][33];
  const int tid = threadIdx.x;         // 0..127
  const int k0  = blockIdx.x * 32;
  const int c0  = blockIdx.y * 32;
  {
    const int tx = tid & 31;           // c within tile
    const int rb = tid >> 5;           // 0..3
    #pragma unroll
    for (int i = 0; i < 8; ++i) {
      int kl = rb * 8 + i;
      tile[kl][tx] = Theta[(size_t)(k0 + kl) * P_DIM + c0 + tx];
    }
  }
  __syncthreads();
  {
    const int cl = tid >> 2;           // 0..31
    const int qt = tid & 3;            // quad within this 32-k tile
    const int c  = c0 + cl;
    const int Q  = blockIdx.x * 4 + qt;  // global quad 0..127
    u16x8 w;
    #pragma unroll
    for (int e = 0; e < 8; ++e) {
      int k = Q * 8 + e;
      float v = tile[qt * 8 + e][cl];
      w[e] = (k < c) ? f2bf(v) : (u16)0;
    }
    *(u16x8*)(Tt + (size_t)c * P_DIM + (size_t)((Q ^ (c & 7)) * 8)) = w;
  }
}

// ---- main GEMM + fused epilogue: 128x128 tile, 8 waves, BK=64, dbuf ----
__global__ void __launch_bounds__(512)
gemm_r11(const u16* __restrict__ Xb, const u16* __restrict__ Tt,
         const float* __restrict__ beta, float* __restrict__ y)
{
  // per buffer: A [128][64] u16 (16 KB) at 0, B [128][64] u16 at 8192
  __shared__ __align__(16) u16 L[2][16384];   // 64 KB total

  // XCD swizzle + heavy-first LPT (R3-verified)
  const int nwg = (N_ROWS / BM) * (P_DIM / BN);    // 4096
  const int swz = (blockIdx.x & 7) * (nwg / 8) + (blockIdx.x >> 3);
  const int bn  = 7 - (swz & 7);
  const int bm  = swz >> 3;
  const int c0  = bn * BN;
  const int m0  = bm * BM;
  const int nkt = (bn + 1) * 2;        // K-steps of 64: 2..16

  const int tid  = threadIdx.x;
  const int lane = tid & 63;
  const int wid  = tid >> 6;           // 0..7
  const int wm   = wid >> 1;           // 0..3  (32-row strip)
  const int wn   = wid & 1;            // 0..1  (64-col half)
  const int l15  = lane & 15;
  const int lg   = lane >> 4;

  // staging: chunk = 8 rows x 64 k (1 KB); lane -> row l>>3, quad l&7.
  // 8 consecutive lanes read 128 B contiguous (quad permutation is already
  // baked into Xb/Tt, segment-local, so segments stay contiguous).
  const int srow = lane >> 3;          // 0..7
  const int sq   = (lane & 7) * 8;     // u16 offset within 64-elem segment

  f32x4 acc[2][4];
  #pragma unroll
  for (int i = 0; i < 2; ++i)
    #pragma unroll
    for (int j = 0; j < 4; ++j)
      acc[i][j] = (f32x4)0.0f;

  #define STAGE(buf_, t_)                                                       \
    {                                                                           \
      const int kk_ = (t_) * BK;                                                \
      _Pragma("unroll")                                                         \
      for (int q = 0; q < 2; ++q) {                                             \
        const int ch_ = wid * 2 + q;                                            \
        gload16(Xb + (size_t)(m0 + ch_ * 8 + srow) * P_DIM + kk_ + sq,          \
                &L[buf_][ch_ * 512]);                                           \
        gload16(Tt + (size_t)(c0 + ch_ * 8 + srow) * P_DIM + kk_ + sq,          \
                &L[buf_][8192 + ch_ * 512]);                                    \
      }                                                                         \
    }

  // prologue
  STAGE(0, 0)
  asm volatile("s_waitcnt vmcnt(0)" ::: "memory");
  __builtin_amdgcn_sched_barrier(0);
  __builtin_amdgcn_s_barrier();
  __builtin_amdgcn_sched_barrier(0);

  for (int t = 0; t < nkt; ++t) {
    const int cur = t & 1;
    const bool pre = (t + 1 < nkt);
    if (pre) STAGE(cur ^ 1, t + 1)

    // fragment ds_reads — quad-XOR conflict-free (2 lanes/bank)
    bf16x8 af[2][2], bfr[2][4];
    #pragma unroll
    for (int kk = 0; kk < 2; ++kk) {
      #pragma unroll
      for (int mi = 0; mi < 2; ++mi) {
        const int rw = wm * 32 + mi * 16 + l15;
        u16x8 v = *(const u16x8*)&L[cur][rw * 64 + ((kk * 4 + lg) ^ (rw & 7)) * 8];
        af[kk][mi] = __builtin_bit_cast(bf16x8, v);
      }
      #pragma unroll
      for (int ni = 0; ni < 4; ++ni) {
        const int cl = wn * 64 + ni * 16 + l15;
        u16x8 v = *(const u16x8*)&L[cur][8192 + cl * 64 + ((kk * 4 + lg) ^ (cl & 7)) * 8];
        bfr[kk][ni] = __builtin_bit_cast(bf16x8, v);
      }
    }

    __builtin_amdgcn_s_setprio(1);
    #pragma unroll
    for (int kk = 0; kk < 2; ++kk)
      #pragma unroll
      for (int mi = 0; mi < 2; ++mi)
        #pragma unroll
        for (int ni = 0; ni < 4; ++ni)
          acc[mi][ni] = __builtin_amdgcn_mfma_f32_16x16x32_bf16(af[kk][mi], bfr[kk][ni], acc[mi][ni], 0, 0, 0);
    __builtin_amdgcn_s_setprio(0);

    if (pre) { asm volatile("s_waitcnt vmcnt(0)" ::: "memory"); }
    __builtin_amdgcn_sched_barrier(0);
    __builtin_amdgcn_s_barrier();
    __builtin_amdgcn_sched_barrier(0);
  }
  #undef STAGE

  // ---- epilogue: y_partial[row] = sum_c (Z[row,c] + beta[c]) * X[row,c] ----
  // C/D layout: col = lane&15, row = (lane>>4)*4 + reg
  float ysum[2][4];
  #pragma unroll
  for (int mi = 0; mi < 2; ++mi)
    #pragma unroll
    for (int r = 0; r < 4; ++r)
      ysum[mi][r] = 0.0f;

  #pragma unroll
  for (int ni = 0; ni < 4; ++ni) {
    const int col = c0 + wn * 64 + ni * 16 + l15;
    const float bta = beta[col];
    const int qx = (col >> 3) & 127;   // global quad of col (within row)
    const int ex = col & 7;
    #pragma unroll
    for (int mi = 0; mi < 2; ++mi) {
      #pragma unroll
      for (int r = 0; r < 4; ++r) {
        const int row = m0 + wm * 32 + mi * 16 + lg * 4 + r;
        float xv = bf2f(Xb[(size_t)row * P_DIM + ((qx ^ (row & 7)) * 8) + ex]);
        ysum[mi][r] += (acc[mi][ni][r] + bta) * xv;
      }
    }
  }

  #pragma unroll
  for (int m = 1; m < 16; m <<= 1)
    #pragma unroll
    for (int mi = 0; mi < 2; ++mi)
      #pragma unroll
      for (int r = 0; r < 4; ++r)
        ysum[mi][r] += __shfl_xor(ysum[mi][r], m);

  if (l15 == 0) {
    #pragma unroll
    for (int mi = 0; mi < 2; ++mi)
      #pragma unroll
      for (int r = 0; r < 4; ++r)
        atomicAdd(&y[m0 + wm * 32 + mi * 16 + lg * 4 + r], ysum[mi][r]);
  }
}

// ================= fallback (R1 kernel, 128x128) if ws too small =================
#define LDT 40
__global__ void __launch_bounds__(256)
fused_quad_fallback(const float* __restrict__ X, const float* __restrict__ beta,
                    const float* __restrict__ Theta, float* __restrict__ y)
{
  __shared__ __align__(16) u16 Alds[128 * LDT];
  __shared__ __align__(16) u16 Blds[128 * LDT];

  const int bid = blockIdx.x;
  const int bn  = bid & 7;
  const int bm  = bid >> 3;
  const int c0  = bn * 128;
  const int m0  = bm * 128;
  const int nkt = (bn + 1) * 4;

  const int tid  = threadIdx.x;
  const int lane = tid & 63;
  const int wid  = tid >> 6;
  const int wm   = wid >> 1;
  const int wn   = wid & 1;
  const int l15  = lane & 15;
  const int lg   = lane >> 4;

  f32x4 acc[4][4];
  #pragma unroll
  for (int i = 0; i < 4; ++i)
    #pragma unroll
    for (int j = 0; j < 4; ++j)
      acc[i][j] = (f32x4)0.0f;

  const int arow  = tid >> 1;
  const int ahalf = (tid & 1) * 16;
  const int kb4 = (tid >> 5) * 4;
  const int cb4 = (tid & 31) * 4;

  for (int kt = 0; kt < nkt; ++kt) {
    const int k0 = kt * 32;
    __syncthreads();
    {
      const f32x4* p = (const f32x4*)(X + (size_t)(m0 + arow) * P_DIM + k0 + ahalf);
      f32x4 v0 = p[0], v1 = p[1], v2 = p[2], v3 = p[3];
      u16x8 w0, w1;
      #pragma unroll
      for (int i = 0; i < 4; ++i) {
        w0[i] = f2bf(v0[i]); w0[i + 4] = f2bf(v1[i]);
        w1[i] = f2bf(v2[i]); w1[i + 4] = f2bf(v3[i]);
      }
      *(u16x8*)&Alds[arow * LDT + ahalf]     = w0;
      *(u16x8*)&Alds[arow * LDT + ahalf + 8] = w1;
    }
    {
      float e[4][4];
      #pragma unroll
      for (int i = 0; i < 4; ++i) {
        f32x4 r = *(const f32x4*)(Theta + (size_t)(k0 + kb4 + i) * P_DIM + c0 + cb4);
        #pragma unroll
        for (int j = 0; j < 4; ++j)
          e[i][j] = ((k0 + kb4 + i) < (c0 + cb4 + j)) ? r[j] : 0.0f;
      }
      #pragma unroll
      for (int j = 0; j < 4; ++j) {
        u16x4 wv;
        #pragma unroll
        for (int i = 0; i < 4; ++i) wv[i] = f2bf(e[i][j]);
        *(u16x4*)&Blds[(cb4 + j) * LDT + kb4] = wv;
      }
    }
    __syncthreads();

    bf16x8 af[4], bfr[4];
    #pragma unroll
    for (int mi = 0; mi < 4; ++mi) {
      u16x8 t = *(const u16x8*)&Alds[(wm * 64 + mi * 16 + l15) * LDT + lg * 8];
      af[mi] = __builtin_bit_cast(bf16x8, t);
    }
    #pragma unroll
    for (int ni = 0; ni < 4; ++ni) {
      u16x8 t = *(const u16x8*)&Blds[(wn * 64 + ni * 16 + l15) * LDT + lg * 8];
      bfr[ni] = __builtin_bit_cast(bf16x8, t);
    }
    #pragma unroll
    for (int mi = 0; mi < 4; ++mi)
      #pragma unroll
      for (int ni = 0; ni < 4; ++ni)
        acc[mi][ni] = __builtin_amdgcn_mfma_f32_16x16x32_bf16(af[mi], bfr[ni], acc[mi][ni], 0, 0, 0);
  }

  float ysum[4][4];
  #pragma unroll
  for (int mi = 0; mi < 4; ++mi)
    #pragma unroll
    for (int r = 0; r < 4; ++r)
      ysum[mi][r] = 0.0f;

  #pragma unroll
  for (int ni = 0; ni < 4; ++ni) {
    const int col = c0 + wn * 64 + ni * 16 + l15;
    const float bta = beta[col];
    #pragma unroll
    for (int mi = 0; mi < 4; ++mi) {
      const int rowb = m0 + wm * 64 + mi * 16 + lg * 4;
      #pragma unroll
      for (int r = 0; r < 4; ++r) {
        float xv = X[(size_t)(rowb + r) * P_DIM + col];
        ysum[mi][r] += (acc[mi][ni][r] + bta) * xv;
      }
    }
  }

  #pragma unroll
  for (int m = 1; m < 16; m <<= 1)
    #pragma unroll
    for (int mi = 0; mi < 4; ++mi)
      #pragma unroll
      for (int r = 0; r < 4; ++r)
        ysum[mi][r] += __shfl_xor(ysum[mi][r], m);

  if (l15 == 0) {
    #pragma unroll
    for (int mi = 0; mi < 4; ++mi)
      #pragma unroll
      for (int r = 0; r < 4; ++r)
        atomicAdd(&y[m0 + wm * 64 + mi * 16 + lg * 4 + r], ysum[mi][r]);
  }
}

extern "C" void kernel_launch(void* const* d_in, const int* in_sizes, int n_in,
                              void* d_out, int out_size, void* d_ws, size_t ws_size,
                              hipStream_t stream) {
  const float* X     = (const float*)d_in[0];
  const float* beta0 = (const float*)d_in[1];
  const float* beta  = (const float*)d_in[2];
  const float* Theta = (const float*)d_in[3];
  float* y = (float*)d_out;

  init_y<<<N_ROWS / 256, 256, 0, stream>>>(y, beta0);

  const size_t need = (size_t)N_ROWS * P_DIM * 2 + (size_t)P_DIM * P_DIM * 2;
  if (ws_size >= need) {
    u16* Xb = (u16*)d_ws;
    u16* Tt = Xb + (size_t)N_ROWS * P_DIM;
    conv_x<<<2048, 256, 0, stream>>>(X, Xb);
    conv_theta<<<dim3(32, 32), 128, 0, stream>>>(Theta, Tt);
    gemm_r11<<<(N_ROWS / BM) * (P_DIM / BN), 512, 0, stream>>>(Xb, Tt, beta, y);
  } else {
    fused_quad_fallback<<<(N_ROWS / 128) * (P_DIM / 128), 256, 0, stream>>>(X, beta, Theta, y);
  }
}

// Round 12
// 180.022 us; speedup vs baseline: 2.5556x; 1.1082x over previous
//
#include <hip/hip_runtime.h>

// y[n] = beta0 + sum_c X[n,c]*(beta[c] + Z[n,c]),  Z = X @ triu(Theta,1)
// R12 = R11 + transposed MFMA (D[c,n], lane=n) -> epilogue reads X
// row-contiguously (u16x4), 2 shfls instead of 16, 1 atomic per row-lane;
// init_y merged into conv_x (one fewer launch). Core unchanged: 128x128
// tile, 8 waves, BK=64 dbuf, segment-local quad-XOR swizzle baked into
// conv outputs (linear gload_lds staging, XOR'd frag reads), XCD swizzle
// + heavy-first LPT.

typedef __bf16 bf16_t;
typedef bf16_t bf16x8 __attribute__((ext_vector_type(8)));
typedef float f32x4 __attribute__((ext_vector_type(4)));
typedef unsigned short u16;
typedef u16 u16x4 __attribute__((ext_vector_type(4)));
typedef u16 u16x8 __attribute__((ext_vector_type(8)));

#define N_ROWS 65536
#define P_DIM  1024
#define BM 128
#define BN 128
#define BK 64

static __device__ __forceinline__ u16 f2bf(float f) {
  unsigned u = __builtin_bit_cast(unsigned, f);
  u += 0x7FFFu + ((u >> 16) & 1u);   // round-to-nearest-even
  return (u16)(u >> 16);
}
static __device__ __forceinline__ float bf2f(u16 v) {
  return __builtin_bit_cast(float, ((unsigned)v) << 16);
}

// global(16B/lane, per-lane src) -> LDS direct (wave-uniform dest + lane*16).
static __device__ __forceinline__ void gload16(const void* g, void* lds_base) {
  __builtin_amdgcn_global_load_lds(
      (const __attribute__((address_space(1))) unsigned char*)g,
      (__attribute__((address_space(3))) unsigned char*)lds_base, 16, 0, 0);
}

__global__ void __launch_bounds__(256)
init_y(float* __restrict__ y, const float* __restrict__ beta0) {
  int i = blockIdx.x * blockDim.x + threadIdx.x;
  if (i < N_ROWS) y[i] = beta0[0];
}

// ---- conv 1: X f32 -> bf16 with segment-local quad-XOR; also inits y ----
__global__ void __launch_bounds__(256)
conv_x(const float* __restrict__ X, u16* __restrict__ Xb,
       float* __restrict__ y, const float* __restrict__ beta0) {
  const size_t tg = (size_t)blockIdx.x * 256 + threadIdx.x;
  if (tg < N_ROWS) y[tg] = beta0[0];
  const size_t nq = (size_t)N_ROWS * P_DIM / 8;
  const size_t stride = (size_t)gridDim.x * 256;
  for (size_t i = tg; i < nq; i += stride) {
    const int row = (int)(i >> 7);
    const int q   = (int)(i & 127);
    f32x4 a = *(const f32x4*)(X + i * 8);
    f32x4 b = *(const f32x4*)(X + i * 8 + 4);
    u16x8 w;
    #pragma unroll
    for (int j = 0; j < 4; ++j) { w[j] = f2bf(a[j]); w[j + 4] = f2bf(b[j]); }
    *(u16x8*)(Xb + (size_t)row * P_DIM + (size_t)((q ^ (row & 7)) * 8)) = w;
  }
}

// ---- conv 2: Tt[c][q'] with q' = q ^ (c&7), quad q = triu-masked bf16 of
// Theta[8q..8q+8, c] (transposed). Same segment-local involution as conv_x.
__global__ void __launch_bounds__(128)
conv_theta(const float* __restrict__ Theta, u16* __restrict__ Tt) {
  __shared__ float tile[32][33];
  const int tid = threadIdx.x;         // 0..127
  const int k0  = blockIdx.x * 32;
  const int c0  = blockIdx.y * 32;
  {
    const int tx = tid & 31;           // c within tile
    const int rb = tid >> 5;           // 0..3
    #pragma unroll
    for (int i = 0; i < 8; ++i) {
      int kl = rb * 8 + i;
      tile[kl][tx] = Theta[(size_t)(k0 + kl) * P_DIM + c0 + tx];
    }
  }
  __syncthreads();
  {
    const int cl = tid >> 2;           // 0..31
    const int qt = tid & 3;            // quad within this 32-k tile
    const int c  = c0 + cl;
    const int Q  = blockIdx.x * 4 + qt;  // global quad 0..127
    u16x8 w;
    #pragma unroll
    for (int e = 0; e < 8; ++e) {
      int k = Q * 8 + e;
      float v = tile[qt * 8 + e][cl];
      w[e] = (k < c) ? f2bf(v) : (u16)0;
    }
    *(u16x8*)(Tt + (size_t)c * P_DIM + (size_t)((Q ^ (c & 7)) * 8)) = w;
  }
}

// ---- main GEMM + fused epilogue: 128x128 tile, 8 waves, BK=64, dbuf ----
__global__ void __launch_bounds__(512)
gemm_r12(const u16* __restrict__ Xb, const u16* __restrict__ Tt,
         const float* __restrict__ beta, float* __restrict__ y)
{
  // per buffer: A [128][64] u16 (16 KB) at 0, B [128][64] u16 at 8192
  __shared__ __align__(16) u16 L[2][16384];   // 64 KB total

  // XCD swizzle + heavy-first LPT (R3/R11-verified)
  const int nwg = (N_ROWS / BM) * (P_DIM / BN);    // 4096
  const int swz = (blockIdx.x & 7) * (nwg / 8) + (blockIdx.x >> 3);
  const int bn  = 7 - (swz & 7);
  const int bm  = swz >> 3;
  const int c0  = bn * BN;
  const int m0  = bm * BM;
  const int nkt = (bn + 1) * 2;        // K-steps of 64: 2..16

  const int tid  = threadIdx.x;
  const int lane = tid & 63;
  const int wid  = tid >> 6;           // 0..7
  const int wm   = wid >> 1;           // 0..3  (32-row strip)
  const int wn   = wid & 1;            // 0..1  (64-col half)
  const int l15  = lane & 15;
  const int lg   = lane >> 4;

  // staging: chunk = 8 rows x 64 k (1 KB); lane -> row l>>3, quad l&7.
  const int srow = lane >> 3;          // 0..7
  const int sq   = (lane & 7) * 8;     // u16 offset within 64-elem segment

  f32x4 acc[2][4];
  #pragma unroll
  for (int i = 0; i < 2; ++i)
    #pragma unroll
    for (int j = 0; j < 4; ++j)
      acc[i][j] = (f32x4)0.0f;

  #define STAGE(buf_, t_)                                                       \
    {                                                                           \
      const int kk_ = (t_) * BK;                                                \
      _Pragma("unroll")                                                         \
      for (int q = 0; q < 2; ++q) {                                             \
        const int ch_ = wid * 2 + q;                                            \
        gload16(Xb + (size_t)(m0 + ch_ * 8 + srow) * P_DIM + kk_ + sq,          \
                &L[buf_][ch_ * 512]);                                           \
        gload16(Tt + (size_t)(c0 + ch_ * 8 + srow) * P_DIM + kk_ + sq,          \
                &L[buf_][8192 + ch_ * 512]);                                    \
      }                                                                         \
    }

  // prologue
  STAGE(0, 0)
  asm volatile("s_waitcnt vmcnt(0)" ::: "memory");
  __builtin_amdgcn_sched_barrier(0);
  __builtin_amdgcn_s_barrier();
  __builtin_amdgcn_sched_barrier(0);

  for (int t = 0; t < nkt; ++t) {
    const int cur = t & 1;
    const bool pre = (t + 1 < nkt);
    if (pre) STAGE(cur ^ 1, t + 1)

    // fragment ds_reads — quad-XOR conflict-free (2 lanes/bank)
    bf16x8 af[2][2], bfr[2][4];
    #pragma unroll
    for (int kk = 0; kk < 2; ++kk) {
      #pragma unroll
      for (int mi = 0; mi < 2; ++mi) {
        const int rw = wm * 32 + mi * 16 + l15;
        u16x8 v = *(const u16x8*)&L[cur][rw * 64 + ((kk * 4 + lg) ^ (rw & 7)) * 8];
        af[kk][mi] = __builtin_bit_cast(bf16x8, v);
      }
      #pragma unroll
      for (int ni = 0; ni < 4; ++ni) {
        const int cl = wn * 64 + ni * 16 + l15;
        u16x8 v = *(const u16x8*)&L[cur][8192 + cl * 64 + ((kk * 4 + lg) ^ (cl & 7)) * 8];
        bfr[kk][ni] = __builtin_bit_cast(bf16x8, v);
      }
    }

    // TRANSPOSED: D[c, n] — A-role operand = B-fragment (c rows),
    // B-role operand = A-fragment (n cols). Lane l15 = n, lg*4+r = c.
    __builtin_amdgcn_s_setprio(1);
    #pragma unroll
    for (int kk = 0; kk < 2; ++kk)
      #pragma unroll
      for (int mi = 0; mi < 2; ++mi)
        #pragma unroll
        for (int ni = 0; ni < 4; ++ni)
          acc[mi][ni] = __builtin_amdgcn_mfma_f32_16x16x32_bf16(bfr[kk][ni], af[kk][mi], acc[mi][ni], 0, 0, 0);
    __builtin_amdgcn_s_setprio(0);

    if (pre) { asm volatile("s_waitcnt vmcnt(0)" ::: "memory"); }
    __builtin_amdgcn_sched_barrier(0);
    __builtin_amdgcn_s_barrier();
    __builtin_amdgcn_sched_barrier(0);
  }
  #undef STAGE

  // ---- epilogue: y_partial[row] = sum_c (Z[row,c] + beta[c]) * X[row,c] ----
  // D[c,n]: n = row = (tile base)+l15, c = c0 + wn*64 + ni*16 + lg*4 + r.
  // X reads are row-contiguous u16x4 (quad-local: (lg*4)&7 in {0,4}).
  float ysum[2];
  ysum[0] = 0.0f; ysum[1] = 0.0f;

  #pragma unroll
  for (int mi = 0; mi < 2; ++mi) {
    const int row = m0 + wm * 32 + mi * 16 + l15;
    const size_t rbase = (size_t)row * P_DIM;
    const int rx = row & 7;
    #pragma unroll
    for (int ni = 0; ni < 4; ++ni) {
      const int cb = c0 + wn * 64 + ni * 16 + lg * 4;   // 4 consecutive cols
      const int qx = cb >> 3;                            // global quad index
      const int ex = cb & 7;                             // 0 or 4
      u16x4 xw = *(const u16x4*)(Xb + rbase + ((size_t)((qx ^ rx) * 8) + ex));
      f32x4 bv = *(const f32x4*)(beta + cb);
      #pragma unroll
      for (int r = 0; r < 4; ++r)
        ysum[mi] += (acc[mi][ni][r] + bv[r]) * bf2f(xw[r]);
    }
  }

  // reduce across lg groups (lanes row-aliased at l15, l15+16, l15+32, l15+48)
  #pragma unroll
  for (int mi = 0; mi < 2; ++mi) {
    ysum[mi] += __shfl_xor(ysum[mi], 16);
    ysum[mi] += __shfl_xor(ysum[mi], 32);
  }
  if (lane < 16) {
    #pragma unroll
    for (int mi = 0; mi < 2; ++mi)
      atomicAdd(&y[m0 + wm * 32 + mi * 16 + l15], ysum[mi]);
  }
}

// ================= fallback (R1 kernel, 128x128) if ws too small =================
#define LDT 40
__global__ void __launch_bounds__(256)
fused_quad_fallback(const float* __restrict__ X, const float* __restrict__ beta,
                    const float* __restrict__ Theta, float* __restrict__ y)
{
  __shared__ __align__(16) u16 Alds[128 * LDT];
  __shared__ __align__(16) u16 Blds[128 * LDT];

  const int bid = blockIdx.x;
  const int bn  = bid & 7;
  const int bm  = bid >> 3;
  const int c0  = bn * 128;
  const int m0  = bm * 128;
  const int nkt = (bn + 1) * 4;

  const int tid  = threadIdx.x;
  const int lane = tid & 63;
  const int wid  = tid >> 6;
  const int wm   = wid >> 1;
  const int wn   = wid & 1;
  const int l15  = lane & 15;
  const int lg   = lane >> 4;

  f32x4 acc[4][4];
  #pragma unroll
  for (int i = 0; i < 4; ++i)
    #pragma unroll
    for (int j = 0; j < 4; ++j)
      acc[i][j] = (f32x4)0.0f;

  const int arow  = tid >> 1;
  const int ahalf = (tid & 1) * 16;
  const int kb4 = (tid >> 5) * 4;
  const int cb4 = (tid & 31) * 4;

  for (int kt = 0; kt < nkt; ++kt) {
    const int k0 = kt * 32;
    __syncthreads();
    {
      const f32x4* p = (const f32x4*)(X + (size_t)(m0 + arow) * P_DIM + k0 + ahalf);
      f32x4 v0 = p[0], v1 = p[1], v2 = p[2], v3 = p[3];
      u16x8 w0, w1;
      #pragma unroll
      for (int i = 0; i < 4; ++i) {
        w0[i] = f2bf(v0[i]); w0[i + 4] = f2bf(v1[i]);
        w1[i] = f2bf(v2[i]); w1[i + 4] = f2bf(v3[i]);
      }
      *(u16x8*)&Alds[arow * LDT + ahalf]     = w0;
      *(u16x8*)&Alds[arow * LDT + ahalf + 8] = w1;
    }
    {
      float e[4][4];
      #pragma unroll
      for (int i = 0; i < 4; ++i) {
        f32x4 r = *(const f32x4*)(Theta + (size_t)(k0 + kb4 + i) * P_DIM + c0 + cb4);
        #pragma unroll
        for (int j = 0; j < 4; ++j)
          e[i][j] = ((k0 + kb4 + i) < (c0 + cb4 + j)) ? r[j] : 0.0f;
      }
      #pragma unroll
      for (int j = 0; j < 4; ++j) {
        u16x4 wv;
        #pragma unroll
        for (int i = 0; i < 4; ++i) wv[i] = f2bf(e[i][j]);
        *(u16x4*)&Blds[(cb4 + j) * LDT + kb4] = wv;
      }
    }
    __syncthreads();

    bf16x8 af[4], bfr[4];
    #pragma unroll
    for (int mi = 0; mi < 4; ++mi) {
      u16x8 t = *(const u16x8*)&Alds[(wm * 64 + mi * 16 + l15) * LDT + lg * 8];
      af[mi] = __builtin_bit_cast(bf16x8, t);
    }
    #pragma unroll
    for (int ni = 0; ni < 4; ++ni) {
      u16x8 t = *(const u16x8*)&Blds[(wn * 64 + ni * 16 + l15) * LDT + lg * 8];
      bfr[ni] = __builtin_bit_cast(bf16x8, t);
    }
    #pragma unroll
    for (int mi = 0; mi < 4; ++mi)
      #pragma unroll
      for (int ni = 0; ni < 4; ++ni)
        acc[mi][ni] = __builtin_amdgcn_mfma_f32_16x16x32_bf16(af[mi], bfr[ni], acc[mi][ni], 0, 0, 0);
  }

  float ysum[4][4];
  #pragma unroll
  for (int mi = 0; mi < 4; ++mi)
    #pragma unroll
    for (int r = 0; r < 4; ++r)
      ysum[mi][r] = 0.0f;

  #pragma unroll
  for (int ni = 0; ni < 4; ++ni) {
    const int col = c0 + wn * 64 + ni * 16 + l15;
    const float bta = beta[col];
    #pragma unroll
    for (int mi = 0; mi < 4; ++mi) {
      const int rowb = m0 + wm * 64 + mi * 16 + lg * 4;
      #pragma unroll
      for (int r = 0; r < 4; ++r) {
        float xv = X[(size_t)(rowb + r) * P_DIM + col];
        ysum[mi][r] += (acc[mi][ni][r] + bta) * xv;
      }
    }
  }

  #pragma unroll
  for (int m = 1; m < 16; m <<= 1)
    #pragma unroll
    for (int mi = 0; mi < 4; ++mi)
      #pragma unroll
      for (int r = 0; r < 4; ++r)
        ysum[mi][r] += __shfl_xor(ysum[mi][r], m);

  if (l15 == 0) {
    #pragma unroll
    for (int mi = 0; mi < 4; ++mi)
      #pragma unroll
      for (int r = 0; r < 4; ++r)
        atomicAdd(&y[m0 + wm * 64 + mi * 16 + lg * 4 + r], ysum[mi][r]);
  }
}

extern "C" void kernel_launch(void* const* d_in, const int* in_sizes, int n_in,
                              void* d_out, int out_size, void* d_ws, size_t ws_size,
                              hipStream_t stream) {
  const float* X     = (const float*)d_in[0];
  const float* beta0 = (const float*)d_in[1];
  const float* beta  = (const float*)d_in[2];
  const float* Theta = (const float*)d_in[3];
  float* y = (float*)d_out;

  const size_t need = (size_t)N_ROWS * P_DIM * 2 + (size_t)P_DIM * P_DIM * 2;
  if (ws_size >= need) {
    u16* Xb = (u16*)d_ws;
    u16* Tt = Xb + (size_t)N_ROWS * P_DIM;
    conv_x<<<2048, 256, 0, stream>>>(X, Xb, y, beta0);
    conv_theta<<<dim3(32, 32), 128, 0, stream>>>(Theta, Tt);
    gemm_r12<<<(N_ROWS / BM) * (P_DIM / BN), 512, 0, stream>>>(Xb, Tt, beta, y);
  } else {
    init_y<<<N_ROWS / 256, 256, 0, stream>>>(y, beta0);
    fused_quad_fallback<<<(N_ROWS / 128) * (P_DIM / 128), 256, 0, stream>>>(X, beta, Theta, y);
  }
}

// Round 13
// 163.569 us; speedup vs baseline: 2.8127x; 1.1006x over previous
//
#include <hip/hip_runtime.h>

// y[n] = beta0 + sum_c X[n,c]*(beta[c] + Z[n,c]),  Z = X @ triu(Theta,1)
// R13: conv_x ELIMINATED — the GEMM stages A directly from f32 X
// (reg-staged: 2x dwordx4 -> 8x f2bf -> 1x ds_write_b128 with write-side
// XOR swizzle). B = pre-swizzled triu^T bf16 Tt (2 MB in d_ws) via
// global_load_lds. BK=32 double-buffer, 8 waves (4wm x 2wn), transposed
// MFMA D[c,n] epilogue reading f32 X row-contiguously. XCD swizzle +
// heavy-first LPT. conv_theta also initializes y = beta0. 2 launches.

typedef __bf16 bf16_t;
typedef bf16_t bf16x8 __attribute__((ext_vector_type(8)));
typedef float f32x4 __attribute__((ext_vector_type(4)));
typedef unsigned short u16;
typedef u16 u16x4 __attribute__((ext_vector_type(4)));
typedef u16 u16x8 __attribute__((ext_vector_type(8)));

#define N_ROWS 65536
#define P_DIM  1024
#define BM 128
#define BN 128
#define BK 32

static __device__ __forceinline__ u16 f2bf(float f) {
  unsigned u = __builtin_bit_cast(unsigned, f);
  u += 0x7FFFu + ((u >> 16) & 1u);   // round-to-nearest-even
  return (u16)(u >> 16);
}

// global(16B/lane, per-lane src) -> LDS direct (wave-uniform dest + lane*16).
static __device__ __forceinline__ void gload16(const void* g, void* lds_base) {
  __builtin_amdgcn_global_load_lds(
      (const __attribute__((address_space(1))) unsigned char*)g,
      (__attribute__((address_space(3))) unsigned char*)lds_base, 16, 0, 0);
}

__global__ void __launch_bounds__(256)
init_y(float* __restrict__ y, const float* __restrict__ beta0) {
  int i = blockIdx.x * blockDim.x + threadIdx.x;
  if (i < N_ROWS) y[i] = beta0[0];
}

// ---- conv: Tt[c][q'] = triu-masked bf16 Theta^T quad, stored at
// q' = q ^ ((c>>1)&3) (segment-local within each 4-quad / 32-k group).
// Also initializes y = beta0 (grid covers 131072 threads >= N_ROWS).
__global__ void __launch_bounds__(128)
conv_theta(const float* __restrict__ Theta, u16* __restrict__ Tt,
           float* __restrict__ y, const float* __restrict__ beta0) {
  __shared__ float tile[32][33];
  const int tid = threadIdx.x;         // 0..127
  const int tg  = (blockIdx.y * gridDim.x + blockIdx.x) * 128 + tid;
  if (tg < N_ROWS) y[tg] = beta0[0];

  const int k0  = blockIdx.x * 32;
  const int c0  = blockIdx.y * 32;
  {
    const int tx = tid & 31;           // c within tile
    const int rb = tid >> 5;           // 0..3
    #pragma unroll
    for (int i = 0; i < 8; ++i) {
      int kl = rb * 8 + i;
      tile[kl][tx] = Theta[(size_t)(k0 + kl) * P_DIM + c0 + tx];
    }
  }
  __syncthreads();
  {
    const int cl = tid >> 2;           // 0..31
    const int qt = tid & 3;            // quad within this 32-k tile
    const int c  = c0 + cl;
    const int Q  = blockIdx.x * 4 + qt;  // global quad 0..127
    u16x8 w;
    #pragma unroll
    for (int e = 0; e < 8; ++e) {
      int k = Q * 8 + e;
      float v = tile[qt * 8 + e][cl];
      w[e] = (k < c) ? f2bf(v) : (u16)0;
    }
    const int qs = (qt ^ ((c >> 1) & 3));          // segment-local store pos
    *(u16x8*)(Tt + (size_t)c * P_DIM + (size_t)(blockIdx.x * 32 + qs * 8)) = w;
  }
}

// ---- main GEMM + fused epilogue: 128x128, 8 waves, BK=32 dbuf,
// A reg-staged f32->bf16, B gload16 ----
__global__ void __launch_bounds__(512)
gemm_r13(const float* __restrict__ X, const u16* __restrict__ Tt,
         const float* __restrict__ beta, float* __restrict__ y)
{
  // per buffer: A [128][32] u16 at 0..4095, B [128][32] u16 at 4096..8191
  __shared__ __align__(16) u16 L[2][8192];   // 32 KB total

  // XCD swizzle + heavy-first LPT (R3/R11/R12-verified): consecutive bids on
  // one XCD share bm (A-panel L2 reuse), bn descending (long-K first).
  const int nwg = (N_ROWS / BM) * (P_DIM / BN);    // 4096
  const int swz = (blockIdx.x & 7) * (nwg / 8) + (blockIdx.x >> 3);
  const int bn  = 7 - (swz & 7);
  const int bm  = swz >> 3;
  const int c0  = bn * BN;
  const int m0  = bm * BM;
  const int nkt = (bn + 1) * 4;        // K-steps of 32: 4..32

  const int tid  = threadIdx.x;
  const int lane = tid & 63;
  const int wid  = tid >> 6;           // 0..7
  const int wm   = wid >> 1;           // 0..3  (32-row strip)
  const int wn   = wid & 1;            // 0..1  (64-col half)
  const int l15  = lane & 15;
  const int lg   = lane >> 4;

  // ---- A staging geometry (reg-staged): thread -> row ar, 8-f32 group ap ----
  const int ar = tid >> 2;             // 0..127
  const int ap = tid & 3;              // quad 0..3 (8 f32 = 64 B)
  const int aq = (ap ^ ((ar >> 1) & 3)) * 8;   // swizzled LDS quad offset (u16)

  // ---- B staging geometry: chunk = wave; 16 rows x 32 k = 1 KB ----
  const int brow = wid * 16 + (lane >> 2);     // c row within tile
  const int bq   = (lane & 3) * 8;             // source quad offset (pre-swizzled)

  f32x4 acc[2][4];
  #pragma unroll
  for (int i = 0; i < 2; ++i)
    #pragma unroll
    for (int j = 0; j < 4; ++j)
      acc[i][j] = (f32x4)0.0f;

  f32x4 av0, av1;   // A staging registers (f32)

  #define STAGE_A_LOAD(t_)                                                      \
    {                                                                           \
      const float* s_ = X + (size_t)(m0 + ar) * P_DIM + (t_) * BK + ap * 8;     \
      av0 = ((const f32x4*)s_)[0];                                              \
      av1 = ((const f32x4*)s_)[1];                                              \
    }
  #define STAGE_A_WRITE(buf_)                                                   \
    {                                                                           \
      u16x8 w_;                                                                 \
      _Pragma("unroll")                                                         \
      for (int j = 0; j < 4; ++j) { w_[j] = f2bf(av0[j]); w_[j + 4] = f2bf(av1[j]); } \
      *(u16x8*)&L[buf_][ar * 32 + aq] = w_;                                     \
    }
  #define STAGE_B(buf_, t_)                                                     \
    gload16(Tt + (size_t)(c0 + brow) * P_DIM + (t_) * BK + bq,                  \
            &L[buf_][4096 + wid * 512]);

  // prologue: tile 0
  STAGE_A_LOAD(0)
  STAGE_B(0, 0)
  asm volatile("s_waitcnt vmcnt(0)" ::: "memory");
  __builtin_amdgcn_sched_barrier(0);
  STAGE_A_WRITE(0)
  asm volatile("s_waitcnt lgkmcnt(0)" ::: "memory");
  __builtin_amdgcn_sched_barrier(0);
  __builtin_amdgcn_s_barrier();
  __builtin_amdgcn_sched_barrier(0);

  for (int t = 0; t < nkt; ++t) {
    const int cur = t & 1;
    const bool pre = (t + 1 < nkt);
    // issue next-tile loads EARLY: global latency hides under frags+MFMA
    if (pre) { STAGE_A_LOAD(t + 1) STAGE_B(cur ^ 1, t + 1) }

    // fragment ds_reads — swizzle (q ^ ((row>>1)&3)) -> ~2-way, free
    bf16x8 af[2], bfr[4];
    #pragma unroll
    for (int mi = 0; mi < 2; ++mi) {
      const int rw = wm * 32 + mi * 16 + l15;
      u16x8 v = *(const u16x8*)&L[cur][rw * 32 + (lg ^ ((rw >> 1) & 3)) * 8];
      af[mi] = __builtin_bit_cast(bf16x8, v);
    }
    #pragma unroll
    for (int ni = 0; ni < 4; ++ni) {
      const int cl = wn * 64 + ni * 16 + l15;
      u16x8 v = *(const u16x8*)&L[cur][4096 + cl * 32 + (lg ^ ((cl >> 1) & 3)) * 8];
      bfr[ni] = __builtin_bit_cast(bf16x8, v);
    }

    // TRANSPOSED MFMA: D[c,n], lane l15 = n (row), lg*4+r = c
    __builtin_amdgcn_s_setprio(1);
    #pragma unroll
    for (int mi = 0; mi < 2; ++mi)
      #pragma unroll
      for (int ni = 0; ni < 4; ++ni)
        acc[mi][ni] = __builtin_amdgcn_mfma_f32_16x16x32_bf16(bfr[ni], af[mi], acc[mi][ni], 0, 0, 0);
    __builtin_amdgcn_s_setprio(0);

    if (pre) {
      asm volatile("s_waitcnt vmcnt(0)" ::: "memory");   // av regs + B gload landed
      __builtin_amdgcn_sched_barrier(0);
      STAGE_A_WRITE(cur ^ 1)
    }
    asm volatile("s_waitcnt lgkmcnt(0)" ::: "memory");   // my ds_writes visible
    __builtin_amdgcn_sched_barrier(0);
    __builtin_amdgcn_s_barrier();
    __builtin_amdgcn_sched_barrier(0);
  }
  #undef STAGE_A_LOAD
  #undef STAGE_A_WRITE
  #undef STAGE_B

  // ---- epilogue: y_partial[row] = sum_c (Z[row,c] + beta[c]) * X[row,c] ----
  // D[c,n]: n = row = base+l15, c = c0 + wn*64 + ni*16 + lg*4 + r. X read f32.
  float ysum[2];
  ysum[0] = 0.0f; ysum[1] = 0.0f;

  #pragma unroll
  for (int mi = 0; mi < 2; ++mi) {
    const int row = m0 + wm * 32 + mi * 16 + l15;
    const float* xr = X + (size_t)row * P_DIM;
    #pragma unroll
    for (int ni = 0; ni < 4; ++ni) {
      const int cb = c0 + wn * 64 + ni * 16 + lg * 4;   // 4 consecutive cols
      f32x4 xw = *(const f32x4*)(xr + cb);
      f32x4 bv = *(const f32x4*)(beta + cb);
      #pragma unroll
      for (int r = 0; r < 4; ++r)
        ysum[mi] += (acc[mi][ni][r] + bv[r]) * xw[r];
    }
  }

  #pragma unroll
  for (int mi = 0; mi < 2; ++mi) {
    ysum[mi] += __shfl_xor(ysum[mi], 16);
    ysum[mi] += __shfl_xor(ysum[mi], 32);
  }
  if (lane < 16) {
    #pragma unroll
    for (int mi = 0; mi < 2; ++mi)
      atomicAdd(&y[m0 + wm * 32 + mi * 16 + l15], ysum[mi]);
  }
}

// ================= fallback (R1 kernel, 128x128) if ws too small =================
#define LDT 40
__global__ void __launch_bounds__(256)
fused_quad_fallback(const float* __restrict__ X, const float* __restrict__ beta,
                    const float* __restrict__ Theta, float* __restrict__ y)
{
  __shared__ __align__(16) u16 Alds[128 * LDT];
  __shared__ __align__(16) u16 Blds[128 * LDT];

  const int bid = blockIdx.x;
  const int bn  = bid & 7;
  const int bm  = bid >> 3;
  const int c0  = bn * 128;
  const int m0  = bm * 128;
  const int nkt = (bn + 1) * 4;

  const int tid  = threadIdx.x;
  const int lane = tid & 63;
  const int wid  = tid >> 6;
  const int wm   = wid >> 1;
  const int wn   = wid & 1;
  const int l15  = lane & 15;
  const int lg   = lane >> 4;

  f32x4 acc[4][4];
  #pragma unroll
  for (int i = 0; i < 4; ++i)
    #pragma unroll
    for (int j = 0; j < 4; ++j)
      acc[i][j] = (f32x4)0.0f;

  const int arow  = tid >> 1;
  const int ahalf = (tid & 1) * 16;
  const int kb4 = (tid >> 5) * 4;
  const int cb4 = (tid & 31) * 4;

  for (int kt = 0; kt < nkt; ++kt) {
    const int k0 = kt * 32;
    __syncthreads();
    {
      const f32x4* p = (const f32x4*)(X + (size_t)(m0 + arow) * P_DIM + k0 + ahalf);
      f32x4 v0 = p[0], v1 = p[1], v2 = p[2], v3 = p[3];
      u16x8 w0, w1;
      #pragma unroll
      for (int i = 0; i < 4; ++i) {
        w0[i] = f2bf(v0[i]); w0[i + 4] = f2bf(v1[i]);
        w1[i] = f2bf(v2[i]); w1[i + 4] = f2bf(v3[i]);
      }
      *(u16x8*)&Alds[arow * LDT + ahalf]     = w0;
      *(u16x8*)&Alds[arow * LDT + ahalf + 8] = w1;
    }
    {
      float e[4][4];
      #pragma unroll
      for (int i = 0; i < 4; ++i) {
        f32x4 r = *(const f32x4*)(Theta + (size_t)(k0 + kb4 + i) * P_DIM + c0 + cb4);
        #pragma unroll
        for (int j = 0; j < 4; ++j)
          e[i][j] = ((k0 + kb4 + i) < (c0 + cb4 + j)) ? r[j] : 0.0f;
      }
      #pragma unroll
      for (int j = 0; j < 4; ++j) {
        u16x4 wv;
        #pragma unroll
        for (int i = 0; i < 4; ++i) wv[i] = f2bf(e[i][j]);
        *(u16x4*)&Blds[(cb4 + j) * LDT + kb4] = wv;
      }
    }
    __syncthreads();

    bf16x8 af[4], bfr[4];
    #pragma unroll
    for (int mi = 0; mi < 4; ++mi) {
      u16x8 t = *(const u16x8*)&Alds[(wm * 64 + mi * 16 + l15) * LDT + lg * 8];
      af[mi] = __builtin_bit_cast(bf16x8, t);
    }
    #pragma unroll
    for (int ni = 0; ni < 4; ++ni) {
      u16x8 t = *(const u16x8*)&Blds[(wn * 64 + ni * 16 + l15) * LDT + lg * 8];
      bfr[ni] = __builtin_bit_cast(bf16x8, t);
    }
    #pragma unroll
    for (int mi = 0; mi < 4; ++mi)
      #pragma unroll
      for (int ni = 0; ni < 4; ++ni)
        acc[mi][ni] = __builtin_amdgcn_mfma_f32_16x16x32_bf16(af[mi], bfr[ni], acc[mi][ni], 0, 0, 0);
  }

  float ysum[4][4];
  #pragma unroll
  for (int mi = 0; mi < 4; ++mi)
    #pragma unroll
    for (int r = 0; r < 4; ++r)
      ysum[mi][r] = 0.0f;

  #pragma unroll
  for (int ni = 0; ni < 4; ++ni) {
    const int col = c0 + wn * 64 + ni * 16 + l15;
    const float bta = beta[col];
    #pragma unroll
    for (int mi = 0; mi < 4; ++mi) {
      const int rowb = m0 + wm * 64 + mi * 16 + lg * 4;
      #pragma unroll
      for (int r = 0; r < 4; ++r) {
        float xv = X[(size_t)(rowb + r) * P_DIM + col];
        ysum[mi][r] += (acc[mi][ni][r] + bta) * xv;
      }
    }
  }

  #pragma unroll
  for (int m = 1; m < 16; m <<= 1)
    #pragma unroll
    for (int mi = 0; mi < 4; ++mi)
      #pragma unroll
      for (int r = 0; r < 4; ++r)
        ysum[mi][r] += __shfl_xor(ysum[mi][r], m);

  if (l15 == 0) {
    #pragma unroll
    for (int mi = 0; mi < 4; ++mi)
      #pragma unroll
      for (int r = 0; r < 4; ++r)
        atomicAdd(&y[m0 + wm * 64 + mi * 16 + lg * 4 + r], ysum[mi][r]);
  }
}

extern "C" void kernel_launch(void* const* d_in, const int* in_sizes, int n_in,
                              void* d_out, int out_size, void* d_ws, size_t ws_size,
                              hipStream_t stream) {
  const float* X     = (const float*)d_in[0];
  const float* beta0 = (const float*)d_in[1];
  const float* beta  = (const float*)d_in[2];
  const float* Theta = (const float*)d_in[3];
  float* y = (float*)d_out;

  const size_t need = (size_t)P_DIM * P_DIM * 2;   // only Tt now (2 MB)
  if (ws_size >= need) {
    u16* Tt = (u16*)d_ws;
    conv_theta<<<dim3(32, 32), 128, 0, stream>>>(Theta, Tt, y, beta0);
    gemm_r13<<<(N_ROWS / BM) * (P_DIM / BN), 512, 0, stream>>>(X, Tt, beta, y);
  } else {
    init_y<<<N_ROWS / 256, 256, 0, stream>>>(y, beta0);
    fused_quad_fallback<<<(N_ROWS / 128) * (P_DIM / 128), 256, 0, stream>>>(X, beta, Theta, y);
  }
}